// Round 7
// baseline (87.223 us; speedup 1.0000x reference)
//
#include <hip/hip_runtime.h>

// SDT forward, fp16 MFMA (fp32 accumulate). M=16/block, grid 512 (2 blocks/CU
// for cross-block phase overlap). Wave = 1 m-tile x 4 n-tiles (min LDS reads).
//   logits = x @ W (fp16; err ~2e-4 vs threshold ~0.13)
//   out = P @ value (fp16 MFMA), P = prod_d max(branch_p,1e-5)
//   reg = sum (-0.5*2^-d/8192)*log(max(p(1-p),1e-5))
// W^T / value^T stored FRAGMENT-MAJOR (lane-linear 1 KB loads).
// MFMA 16x16x32 layouts (HW-verified r2-r6): A/B^T lane&15->row, (lane>>4)*8->k;
// C/D: col=lane&15, row=(lane>>4)*4+reg.

typedef __attribute__((ext_vector_type(8))) _Float16 half8;
typedef __attribute__((ext_vector_type(4))) _Float16 half4;
typedef __attribute__((ext_vector_type(4))) float floatx4;

constexpr int O = 64;
constexpr int XSTR = 520;   // x-tile LDS row stride (halfs)
constexpr int PSTR = 280;   // P_h row stride (halfs)
constexpr int LSTR = 260;   // L_s row stride (floats)

// ---- pre: W^T fp16 frag-major (128 blk x 4 k-rows); value^T (32 blk); reg=0 ----
// wt layout: block (T*16+c) of 1024 B; lane=(q*16+r16); elem j:
//   wt[(T*16+c)*512 + lane*8 + j] = W[k=c*32+q*8+j][n=T*16+r16]
__global__ __launch_bounds__(256) void sdt_pre(
    const float* __restrict__ Ws, const float* __restrict__ value,
    _Float16* __restrict__ wt, _Float16* __restrict__ vt,
    float* __restrict__ reg_slot)
{
  const int bid = blockIdx.x, t = threadIdx.x;
  if (bid < 128) {                     // W: 4 k-rows per block, coalesced reads
    const int k0 = bid * 4;
    const int n = t;                   // 0..255
    const int T = n >> 4, r = n & 15;
    const int c = k0 >> 5, q = (k0 >> 3) & 3, j0 = k0 & 7;
    _Float16 v4[4];
#pragma unroll
    for (int kk = 0; kk < 4; ++kk) {
      float f = (n < 255) ? Ws[(size_t)(k0 + kk) * 255 + n] : 0.f;
      v4[kk] = (_Float16)f;
    }
    *(half4*)&wt[(size_t)(T * 16 + c) * 512 + (q * 16 + r) * 8 + j0] = *(half4*)v4;
  } else {                             // value^T frag-major: 512 elems per block
    const int e0 = (bid - 128) * 512 + t;
#pragma unroll
    for (int j = 0; j < 2; ++j) {
      int e = e0 + j * 256;            // enumerate (k,n): n=e&63, k=e>>6
      int k = e >> 6, n = e & 63;
      float f = value[(size_t)k * O + n];
      int T = n >> 4, r = n & 15, kc = k >> 5, q = (k >> 3) & 3, jj = k & 7;
      vt[(size_t)(T * 8 + kc) * 512 + (q * 16 + r) * 8 + jj] = (_Float16)f;
    }
    if (bid == 128 && t == 0) *reg_slot = 0.f;
  }
}

__global__ __launch_bounds__(256, 2) void sdt_main(
    const float* __restrict__ x, const _Float16* __restrict__ wt,
    const _Float16* __restrict__ vt, const float* __restrict__ bs,
    float* __restrict__ out, float* __restrict__ reg_out)
{
  // Overlay: phase 1 x-tile fp16 (16640 B) / phase 2 L_s (16640 B); P_h after.
  __shared__ __align__(16) char smem[16640 + 8960];
  _Float16* xh_s = (_Float16*)smem;              // [16][520]
  float*    L_s  = (float*)smem;                 // [16][260]
  _Float16* P_h  = (_Float16*)(smem + 16640);    // [16][280]
  __shared__ float red_s[4];

  const int t = threadIdx.x, lane = t & 63, w = t >> 6;   // 4 waves
  const int q = lane >> 4, r16 = lane & 15;
  const int R0 = blockIdx.x * 16;

  // -------- stage + convert x tile once (coalesced) --------
  {
    const int row = t >> 4, l4 = (t & 15) * 4;
    const float* xrow = x + (size_t)(R0 + row) * 512;
#pragma unroll
    for (int i = 0; i < 8; ++i) {
      const int k = l4 + i * 64;
      float4 v = *(const float4*)(xrow + k);
      half4 h = {(_Float16)v.x, (_Float16)v.y, (_Float16)v.z, (_Float16)v.w};
      *(half4*)&xh_s[row * XSTR + k] = h;
    }
  }
  __syncthreads();

  // -------- barrier-free K-loop: 16 chunks of K=32, 4 MFMA each --------
  // wave w: n-tiles T = w*4+i (i=0..3), m-tile 0 (rows 0..15)
  const _Float16* pb0 = wt + (size_t)(w * 4 + 0) * 16 * 512 + lane * 8;
  const _Float16* pb1 = wt + (size_t)(w * 4 + 1) * 16 * 512 + lane * 8;
  const _Float16* pb2 = wt + (size_t)(w * 4 + 2) * 16 * 512 + lane * 8;
  const _Float16* pb3 = wt + (size_t)(w * 4 + 3) * 16 * 512 + lane * 8;
  const int a0off = r16 * XSTR + q * 8;

  floatx4 acc0 = {0,0,0,0}, acc1 = {0,0,0,0}, acc2 = {0,0,0,0}, acc3 = {0,0,0,0};
  half8 B0 = *(const half8*)pb0, B1 = *(const half8*)pb1;
  half8 B2 = *(const half8*)pb2, B3 = *(const half8*)pb3;

#pragma unroll
  for (int c = 0; c < 16; ++c) {
    half8 n0, n1, n2, n3;
    if (c < 15) {
      n0 = *(const half8*)(pb0 + (c + 1) * 512);
      n1 = *(const half8*)(pb1 + (c + 1) * 512);
      n2 = *(const half8*)(pb2 + (c + 1) * 512);
      n3 = *(const half8*)(pb3 + (c + 1) * 512);
    }
    half8 a = *(const half8*)&xh_s[a0off + c * 32];
    acc0 = __builtin_amdgcn_mfma_f32_16x16x32_f16(a, B0, acc0, 0, 0, 0);
    acc1 = __builtin_amdgcn_mfma_f32_16x16x32_f16(a, B1, acc1, 0, 0, 0);
    acc2 = __builtin_amdgcn_mfma_f32_16x16x32_f16(a, B2, acc2, 0, 0, 0);
    acc3 = __builtin_amdgcn_mfma_f32_16x16x32_f16(a, B3, acc3, 0, 0, 0);
    if (c < 15) { B0 = n0; B1 = n1; B2 = n2; B3 = n3; }
  }
  __syncthreads();   // all x-tile reads done before L_s overlays it

  // -------- epilogue: C frags -> L_s --------
  {
#pragma unroll
    for (int i = 0; i < 4; ++i) {
      const floatx4& A = (i == 0) ? acc0 : (i == 1) ? acc1 : (i == 2) ? acc2 : acc3;
      const int c0 = (w * 4 + i) * 16 + r16;
#pragma unroll
      for (int r = 0; r < 4; ++r)
        L_s[(q * 4 + r) * LSTR + c0] = A[r];
    }
  }
  __syncthreads();

  // -------- phase 2a: sigmoid (+bias), reg --------
  {
    const int col = t;
    float rsum = 0.f;
    if (col < 255) {
      float b = bs[col];
#pragma unroll 4
      for (int r = 0; r < 16; ++r) {
        float z = L_s[r * LSTR + col] + b;
        float p = 1.f / (1.f + __expf(-z));
        L_s[r * LSTR + col] = p;                  // exclusive column owner
        rsum += __logf(fmaxf(p * (1.f - p), 1e-5f));
      }
      int dd = 31 - __clz(col + 1);
      rsum *= -0.5f / (8192.0f * (float)(1 << dd));
    }
#pragma unroll
    for (int off = 32; off; off >>= 1) rsum += __shfl_down(rsum, off, 64);
    if (lane == 0) red_s[w] = rsum;
  }
  __syncthreads();
  if (t == 0)
    atomicAdd(reg_out, red_s[0] + red_s[1] + red_s[2] + red_s[3]);

  // -------- phase 2b: path products, 8 leaves x 2 rows per thread --------
  {
    const int g8 = t & 31, rp = t >> 5;
    const int Lb = g8 * 8;
#pragma unroll
    for (int rr = 0; rr < 2; ++rr) {
      const int row = rp * 2 + rr;
      const float* Lr = &L_s[row * LSTR];
      float pre = 1.f;
#pragma unroll
      for (int dd = 0; dd < 5; ++dd) {
        float p = Lr[(1 << dd) - 1 + (Lb >> (8 - dd))];
        float br = ((Lb >> (7 - dd)) & 1) ? (1.f - p) : p;
        pre *= fmaxf(br, 1e-5f);
      }
      float p5 = Lr[31 + g8];
      float s5a = fmaxf(p5, 1e-5f), s5b = fmaxf(1.f - p5, 1e-5f);
      float p6a = Lr[63 + 2 * g8], p6b = Lr[63 + 2 * g8 + 1];
      float p7v[4];
#pragma unroll
      for (int m = 0; m < 4; ++m) p7v[m] = Lr[127 + 4 * g8 + m];
      _Float16 ph[8];
#pragma unroll
      for (int j = 0; j < 8; ++j) {
        float s5 = (j & 4) ? s5b : s5a;
        float p6 = (j & 4) ? p6b : p6a;
        float s6 = fmaxf((j & 2) ? (1.f - p6) : p6, 1e-5f);
        float p7 = p7v[j >> 1];
        float s7 = fmaxf((j & 1) ? (1.f - p7) : p7, 1e-5f);
        ph[j] = (_Float16)(pre * s5 * s6 * s7);
      }
      *(half8*)&P_h[row * PSTR + Lb] = *(half8*)ph;
    }
  }
  __syncthreads();

  // -------- phase 2c: out[16][64] = P @ value via fp16 MFMA --------
  {
    floatx4 C = {0, 0, 0, 0};
    const _Float16* vb = vt + (size_t)(w * 8) * 512 + lane * 8;
    const _Float16* pa = &P_h[r16 * PSTR + q * 8];
#pragma unroll
    for (int kc = 0; kc < 8; ++kc) {
      half8 A8 = *(const half8*)(pa + kc * 32);
      half8 B8 = *(const half8*)(vb + kc * 512);
      C = __builtin_amdgcn_mfma_f32_16x16x32_f16(A8, B8, C, 0, 0, 0);
    }
    const int col = w * 16 + r16;
#pragma unroll
    for (int r = 0; r < 4; ++r)
      out[(size_t)(R0 + q * 4 + r) * O + col] = C[r];
  }
}

extern "C" void kernel_launch(void* const* d_in, const int* in_sizes, int n_in,
                              void* d_out, int out_size, void* d_ws, size_t ws_size,
                              hipStream_t stream) {
  const float* x     = (const float*)d_in[0];
  const float* Ws    = (const float*)d_in[1];
  const float* bs    = (const float*)d_in[2];
  const float* value = (const float*)d_in[3];
  float* outp = (float*)d_out;
  float* reg_slot = outp + (size_t)8192 * O;          // index 524288
  _Float16* wt = (_Float16*)d_ws;                     // frag-major W^T fp16, 256 KB
  _Float16* vt = wt + 256 * 512;                      // frag-major value^T fp16, 32 KB

  sdt_pre<<<160, 256, 0, stream>>>(Ws, value, wt, vt, reg_slot);
  sdt_main<<<512, 256, 0, stream>>>(x, wt, vt, bs, outp, reg_slot);
}

// Round 8
// 84.658 us; speedup vs baseline: 1.0303x; 1.0303x over previous
//
#include <hip/hip_runtime.h>

// SDT forward, fp16 MFMA (fp32 accumulate). r6 structure (M=32, grid 256,
// 512 thr, wave = 2m x 2n tiles) + depth-3 B prefetch + launch_bounds(512,4)
// to guarantee 2 blocks/CU.
//   logits = x @ W (fp16; err ~2e-4 vs threshold ~0.13)
//   out = P @ value (fp16 MFMA), P = prod_d max(branch_p,1e-5)
//   reg = sum (-0.5*2^-d/8192)*log(max(p(1-p),1e-5))
// W^T / value^T stored FRAGMENT-MAJOR in d_ws (lane-linear 1 KB loads).
// MFMA 16x16x32 layouts (HW-verified r2-r7): A/B^T lane&15->row, (lane>>4)*8->k;
// C/D: col=lane&15, row=(lane>>4)*4+reg.

typedef __attribute__((ext_vector_type(8))) _Float16 half8;
typedef __attribute__((ext_vector_type(4))) _Float16 half4;
typedef __attribute__((ext_vector_type(4))) float floatx4;

constexpr int O = 64;
constexpr int XSTR = 520;   // x-tile LDS row stride (halfs)
constexpr int PSTR = 280;   // P_h row stride (halfs)
constexpr int LSTR = 260;   // L_s row stride (floats)

// ---- pre: W^T fp16 frag-major; value^T fp16 frag-major; zero reg ----
// wt layout: block (T*16+c) of 1024 B; lane=(q*16+r16); elem j:
//   wt[(T*16+c)*512 + lane*8 + j] = W[k=c*32+q*8+j][n=T*16+r16]
__global__ __launch_bounds__(256) void sdt_pre(
    const float* __restrict__ Ws, const float* __restrict__ value,
    _Float16* __restrict__ wt, _Float16* __restrict__ vt,
    float* __restrict__ reg_slot)
{
  const int bid = blockIdx.x, t = threadIdx.x;
  if (bid < 64) {                      // W: 8 k-rows per block, coalesced reads
    const int k0 = bid * 8;
    const int n = t;                   // 0..255
    const int T = n >> 4, r = n & 15;
    const int c = k0 >> 5, q = (k0 >> 3) & 3;
    _Float16 v8[8];
#pragma unroll
    for (int kk = 0; kk < 8; ++kk) {
      float f = (n < 255) ? Ws[(size_t)(k0 + kk) * 255 + n] : 0.f;
      v8[kk] = (_Float16)f;
    }
    *(half8*)&wt[(size_t)(T * 16 + c) * 512 + (q * 16 + r) * 8] = *(half8*)v8;
  } else {                             // value^T: 64 k-rows per block
    const int k0 = (bid - 64) * 64;
#pragma unroll
    for (int j = 0; j < 16; ++j) {
      int e = t + j * 256;             // 0..4095
      int k = k0 + (e >> 6), n = e & 63;
      float f = value[(size_t)k * O + n];
      int T = n >> 4, r = n & 15, kc = k >> 5, q = (k >> 3) & 3, jj = k & 7;
      vt[(size_t)(T * 8 + kc) * 512 + (q * 16 + r) * 8 + jj] = (_Float16)f;
    }
    if (bid == 64 && t == 0) *reg_slot = 0.f;
  }
}

__global__ __launch_bounds__(512, 4) void sdt_main(
    const float* __restrict__ x, const _Float16* __restrict__ wt,
    const _Float16* __restrict__ vt, const float* __restrict__ bs,
    float* __restrict__ out, float* __restrict__ reg_out)
{
  // Overlay: phase 1 x-tile fp16 (33280 B) / phase 2 L_s (33280 B) + P_h.
  __shared__ __align__(16) char smem[33280 + 17920];
  _Float16* xh_s = (_Float16*)smem;              // [32][520]
  float*    L_s  = (float*)smem;                 // [32][260]
  _Float16* P_h  = (_Float16*)(smem + 33280);    // [32][280]
  __shared__ float red_s[8];

  const int t = threadIdx.x, lane = t & 63, w = t >> 6;   // 8 waves
  const int q = lane >> 4, r16 = lane & 15;
  const int R0 = blockIdx.x * 32;

  // -------- stage + convert x tile once (coalesced) --------
  {
    const int row = t >> 4, l4 = (t & 15) * 4;
    const float* xrow = x + (size_t)(R0 + row) * 512;
#pragma unroll
    for (int i = 0; i < 8; ++i) {
      const int k = l4 + i * 64;
      float4 v = *(const float4*)(xrow + k);
      half4 h = {(_Float16)v.x, (_Float16)v.y, (_Float16)v.z, (_Float16)v.w};
      *(half4*)&xh_s[row * XSTR + k] = h;
    }
  }
  __syncthreads();

  // -------- barrier-free K-loop: 16 chunks of K=32, depth-3 B prefetch --------
  const _Float16* pb0 = wt + (size_t)(2 * w) * 16 * 512 + lane * 8;
  const _Float16* pb1 = wt + (size_t)(2 * w + 1) * 16 * 512 + lane * 8;
  const int a0off = r16 * XSTR, a1off = (16 + r16) * XSTR;

  floatx4 acc00 = {0,0,0,0}, acc01 = {0,0,0,0}, acc10 = {0,0,0,0}, acc11 = {0,0,0,0};
  half8 B0[4], B1[4];
#pragma unroll
  for (int s = 0; s < 3; ++s) {
    B0[s] = *(const half8*)(pb0 + s * 512);
    B1[s] = *(const half8*)(pb1 + s * 512);
  }

#pragma unroll
  for (int c = 0; c < 16; ++c) {
    if (c + 3 < 16) {
      B0[(c + 3) & 3] = *(const half8*)(pb0 + (c + 3) * 512);
      B1[(c + 3) & 3] = *(const half8*)(pb1 + (c + 3) * 512);
    }
    half8 a0 = *(const half8*)&xh_s[a0off + c * 32 + q * 8];
    half8 a1 = *(const half8*)&xh_s[a1off + c * 32 + q * 8];
    acc00 = __builtin_amdgcn_mfma_f32_16x16x32_f16(a0, B0[c & 3], acc00, 0, 0, 0);
    acc01 = __builtin_amdgcn_mfma_f32_16x16x32_f16(a0, B1[c & 3], acc01, 0, 0, 0);
    acc10 = __builtin_amdgcn_mfma_f32_16x16x32_f16(a1, B0[c & 3], acc10, 0, 0, 0);
    acc11 = __builtin_amdgcn_mfma_f32_16x16x32_f16(a1, B1[c & 3], acc11, 0, 0, 0);
  }
  __syncthreads();   // all x-tile reads done before L_s overlays it

  // -------- epilogue: C frags -> L_s --------
  {
    const int c0 = w * 32 + r16, c1 = c0 + 16;
#pragma unroll
    for (int r = 0; r < 4; ++r) {
      int row0 = q * 4 + r, row1 = row0 + 16;
      L_s[row0 * LSTR + c0] = acc00[r];
      L_s[row0 * LSTR + c1] = acc01[r];
      L_s[row1 * LSTR + c0] = acc10[r];
      L_s[row1 * LSTR + c1] = acc11[r];
    }
  }
  __syncthreads();

  // -------- phase 2a: sigmoid (+bias), reg --------
  {
    const int col = t & 255, half = t >> 8;
    float rsum = 0.f;
    if (col < 255) {
      float b = bs[col];
      for (int r = half * 16; r < half * 16 + 16; ++r) {
        float z = L_s[r * LSTR + col] + b;
        float p = 1.f / (1.f + __expf(-z));
        L_s[r * LSTR + col] = p;                  // exclusive (col, half) owner
        rsum += __logf(fmaxf(p * (1.f - p), 1e-5f));
      }
      int dd = 31 - __clz(col + 1);
      rsum *= -0.5f / (8192.0f * (float)(1 << dd));
    }
#pragma unroll
    for (int off = 32; off; off >>= 1) rsum += __shfl_down(rsum, off, 64);
    if (lane == 0) red_s[w] = rsum;
  }
  __syncthreads();
  if (t == 0) {
    float s = 0.f;
#pragma unroll
    for (int i = 0; i < 8; ++i) s += red_s[i];
    atomicAdd(reg_out, s);
  }

  // -------- phase 2b: path products, 8 leaves x 2 rows per thread --------
  {
    const int g8 = t & 31, rp = t >> 5;
    const int Lb = g8 * 8;
#pragma unroll
    for (int rr = 0; rr < 2; ++rr) {
      const int row = rp * 2 + rr;
      const float* Lr = &L_s[row * LSTR];
      float pre = 1.f;
#pragma unroll
      for (int dd = 0; dd < 5; ++dd) {
        float p = Lr[(1 << dd) - 1 + (Lb >> (8 - dd))];
        float br = ((Lb >> (7 - dd)) & 1) ? (1.f - p) : p;
        pre *= fmaxf(br, 1e-5f);
      }
      float p5 = Lr[31 + g8];
      float s5a = fmaxf(p5, 1e-5f), s5b = fmaxf(1.f - p5, 1e-5f);
      float p6a = Lr[63 + 2 * g8], p6b = Lr[63 + 2 * g8 + 1];
      float p7v[4];
#pragma unroll
      for (int m = 0; m < 4; ++m) p7v[m] = Lr[127 + 4 * g8 + m];
      _Float16 ph[8];
#pragma unroll
      for (int j = 0; j < 8; ++j) {
        float s5 = (j & 4) ? s5b : s5a;
        float p6 = (j & 4) ? p6b : p6a;
        float s6 = fmaxf((j & 2) ? (1.f - p6) : p6, 1e-5f);
        float p7 = p7v[j >> 1];
        float s7 = fmaxf((j & 1) ? (1.f - p7) : p7, 1e-5f);
        ph[j] = (_Float16)(pre * s5 * s6 * s7);
      }
      *(half8*)&P_h[row * PSTR + Lb] = *(half8*)ph;
    }
  }
  __syncthreads();

  // -------- phase 2c: out[32][64] = P @ value via fp16 MFMA --------
  {
    const int tm = w & 1, tn = w >> 1;       // 2 m-tiles x 4 n-tiles of 16
    floatx4 C = {0, 0, 0, 0};
    const _Float16* vb = vt + (size_t)(tn * 8) * 512 + lane * 8;
    const _Float16* pa = &P_h[(tm * 16 + r16) * PSTR + q * 8];
#pragma unroll
    for (int kc = 0; kc < 8; ++kc) {
      half8 A8 = *(const half8*)(pa + kc * 32);
      half8 B8 = *(const half8*)(vb + kc * 512);
      C = __builtin_amdgcn_mfma_f32_16x16x32_f16(A8, B8, C, 0, 0, 0);
    }
    const int col = tn * 16 + r16;
#pragma unroll
    for (int r = 0; r < 4; ++r) {
      int row = tm * 16 + q * 4 + r;
      out[(size_t)(R0 + row) * O + col] = C[r];
    }
  }
}

extern "C" void kernel_launch(void* const* d_in, const int* in_sizes, int n_in,
                              void* d_out, int out_size, void* d_ws, size_t ws_size,
                              hipStream_t stream) {
  const float* x     = (const float*)d_in[0];
  const float* Ws    = (const float*)d_in[1];
  const float* bs    = (const float*)d_in[2];
  const float* value = (const float*)d_in[3];
  float* outp = (float*)d_out;
  float* reg_slot = outp + (size_t)8192 * O;          // index 524288
  _Float16* wt = (_Float16*)d_ws;                     // frag-major W^T fp16, 256 KB
  _Float16* vt = wt + 256 * 512;                      // frag-major value^T fp16, 32 KB

  sdt_pre<<<68, 256, 0, stream>>>(Ws, value, wt, vt, reg_slot);
  sdt_main<<<256, 512, 0, stream>>>(x, wt, vt, bs, outp, reg_slot);
}